// Round 3
// baseline (82498.993 us; speedup 1.0000x reference)
//
#include <hip/hip_runtime.h>
#include <math.h>

#define HD 1024
#define BB 50
#define SS 457
#define TT 32
#define VV 27

#define KC 64      // k-chunk staged in LDS
#define HSTR 68    // LDS row stride (dwords): stride%32==4 -> b128 reads tile all banks

// ---------------------------------------------------------------------------
// Generic fused row-dot + GRU-gate kernel.
// 1024 threads = 16 waves = 4 row-groups x 4 k-splits. lane = batch (50 of 64).
// Each row-group owns RPG weight rows; k-split partials reduced via two LDS
// slabs in fixed order (deterministic, no atomics).
// mode 0: encoder phase p: blk<86 -> layer0 (JT=12, gate w/ inline 3-input gi),
//                          blk>=86 -> layer1 (dual-source JT=6, writes enc[p-1])
// mode 1: dec D1: blk<171 -> dec layer0 (dual, gi source = emb[tok[b]] gather),
//                 blk>=171 -> gh1 = h1 @ dWhh1 -> scratch (no gate)
// mode 2: dec D2: gi1 = h0new @ dWih1, gate with scratch gh -> h1new + comb[:,0:1024]
// mode 3: attn_fc: rows=12 (RPG=3), K=2048, relu -> hfc
// ---------------------------------------------------------------------------
template<int RPG>
__global__ __launch_bounds__(1024) void rowdot_kernel(
    int mode, int p,
    // single role:
    const float* __restrict__ Ws,
    const float* __restrict__ srcS,
    const float* __restrict__ bihS, const float* __restrict__ bhhS,
    const float* __restrict__ hvS,
    float* __restrict__ outS,
    // dual role:
    const float* __restrict__ Wgi, const float* __restrict__ Wgh,
    const float* __restrict__ srcGI, const float* __restrict__ srcGH,
    const float* __restrict__ bihD, const float* __restrict__ bhhD,
    const float* __restrict__ hvD,
    float* __restrict__ outD, float* __restrict__ encD,
    // extras:
    const float* __restrict__ x, const float* __restrict__ Wih0,
    const float* __restrict__ emb, const int* __restrict__ tok,
    const float* __restrict__ scr_r, float* __restrict__ scr_w,
    float* __restrict__ comb)
{
  __shared__ __align__(16) float hs[2][64][HSTR];
  __shared__ float acc2[2][36][64];

  const int tid = threadIdx.x;
  const int blk = blockIdx.x;

  bool isDual; int j0; int K; int gateType; int gather = 0;
  const float* W0 = nullptr; const float* W1 = nullptr;
  const float* sA = nullptr; const float* sB = nullptr;

  if (mode == 0) {
    if (blk < 86) {
      if (p == 457) return;
      isDual = false; j0 = blk * 12; K = 1024; gateType = 0; W0 = Ws; sA = srcS;
    } else {
      if (p == 0) return;
      isDual = true; j0 = (blk - 86) * 6; K = 1024; gateType = 1;
      W0 = Wgi; W1 = Wgh; sA = srcGI; sB = srcGH;
    }
  } else if (mode == 1) {
    if (blk < 171) {
      isDual = true; j0 = blk * 6; K = 1024; gateType = 1; gather = 1;
      W0 = Wgi; W1 = Wgh; sA = srcGI; sB = srcGH;
    } else {
      isDual = false; j0 = (blk - 171) * 12; K = 1024; gateType = 2; W0 = Ws; sA = srcS;
    }
  } else if (mode == 2) {
    isDual = false; j0 = blk * 12; K = 1024; gateType = 3; W0 = Ws; sA = srcS;
  } else {
    isDual = false; j0 = blk * 12; K = 2048; gateType = 4; W0 = Ws; sA = srcS;
  }

  const int wv = __builtin_amdgcn_readfirstlane(tid >> 6);
  const int lane = tid & 63;
  const int rg = wv & 3, kh = wv >> 2;
  const int srcsel = isDual ? (rg >> 1) : 0;

  // uniform weight-row pointers for this wave
  const float* wp[RPG];
#pragma unroll
  for (int rr = 0; rr < RPG; ++rr) {
    int lr = rg * RPG + rr;
    int wrow;
    if (gateType == 4) {
      wrow = j0 + lr; if (wrow > 1023) wrow = 1023;
    } else if (isDual) {
      int lr2 = (rg & 1) * RPG + rr;          // 0..17 within its source
      int g = lr2 / 6, jl = lr2 % 6;
      int j = j0 + jl; if (j > 1023) j = 1023;
      wrow = g * 1024 + j;
    } else {
      int g = lr / 12, jl = lr % 12;
      int j = j0 + jl; if (j > 1023) j = 1023;
      wrow = g * 1024 + j;
    }
    const float* Wsel = (isDual && (rg >> 1)) ? W1 : W0;
    wp[rr] = Wsel + (size_t)wrow * K;
  }

  const int nst = isDual ? 1600 : 800;   // float4s staged per chunk
  const int nch = K / KC;

  auto rowp = [&](int sel, int b) -> const float* {
    if (sel) return sB + (size_t)b * K;
    if (gather) return emb + (size_t)tok[b] * HD;
    return sA + (size_t)b * K;
  };

  float4 pre0 = make_float4(0.f, 0.f, 0.f, 0.f);
  float4 pre1 = make_float4(0.f, 0.f, 0.f, 0.f);

  // prefetch chunk 0 into registers
  if (tid < nst) { int sel = tid >= 800; int e = tid - (sel ? 800 : 0);
                   pre0 = *(const float4*)(rowp(sel, e >> 4) + (e & 15) * 4); }
  if (isDual && tid + 1024 < nst) { int e = tid + 224;
                   pre1 = *(const float4*)(rowp(1, e >> 4) + (e & 15) * 4); }

  float acc[RPG];
#pragma unroll
  for (int r = 0; r < RPG; ++r) acc[r] = 0.f;

  for (int c = 0; c < nch; ++c) {
    const int kb = c * KC;
    __syncthreads();   // previous chunk fully consumed
    if (tid < nst) { int sel = tid >= 800; int e = tid - (sel ? 800 : 0);
                     *(float4*)&hs[sel][e >> 4][(e & 15) * 4] = pre0; }
    if (isDual && tid + 1024 < nst) { int e = tid + 224;
                     *(float4*)&hs[1][e >> 4][(e & 15) * 4] = pre1; }
    __syncthreads();
    if (c + 1 < nch) {   // issue next-chunk loads early; latency hides under FMAs
      const int kb2 = kb + KC;
      if (tid < nst) { int sel = tid >= 800; int e = tid - (sel ? 800 : 0);
                       pre0 = *(const float4*)(rowp(sel, e >> 4) + kb2 + (e & 15) * 4); }
      if (isDual && tid + 1024 < nst) { int e = tid + 224;
                       pre1 = *(const float4*)(rowp(1, e >> 4) + kb2 + (e & 15) * 4); }
    }
#pragma unroll
    for (int g4 = 0; g4 < 4; ++g4) {
      const int ko = kh * 16 + g4 * 4;
      const float4 hv = *(const float4*)&hs[srcsel][lane][ko];
#pragma unroll
      for (int rr = 0; rr < RPG; ++rr) {
        const float4 w4 = *(const float4*)(wp[rr] + kb + ko);
        acc[rr] = fmaf(hv.x, w4.x, acc[rr]);
        acc[rr] = fmaf(hv.y, w4.y, acc[rr]);
        acc[rr] = fmaf(hv.z, w4.z, acc[rr]);
        acc[rr] = fmaf(hv.w, w4.w, acc[rr]);
      }
    }
  }

  // deterministic k-split reduction: kh0/kh1 write slabs, kh2/kh3 add
  if (kh < 2) {
#pragma unroll
    for (int rr = 0; rr < RPG; ++rr) acc2[kh][rg * RPG + rr][lane] = acc[rr];
  }
  __syncthreads();
  if (kh >= 2) {
#pragma unroll
    for (int rr = 0; rr < RPG; ++rr) acc2[kh - 2][rg * RPG + rr][lane] += acc[rr];
  }
  __syncthreads();

  // ---- gate / epilogue ----
  if (gateType == 0) {           // encoder layer0
    if (tid < 600) {
      int jl = tid / 50, b = tid - jl * 50;
      int j = j0 + jl;
      if (j < 1024) {
        float ghr = acc2[0][jl][b]    + acc2[1][jl][b]    + bhhS[j];
        float ghz = acc2[0][12+jl][b] + acc2[1][12+jl][b] + bhhS[1024 + j];
        float ghn = acc2[0][24+jl][b] + acc2[1][24+jl][b] + bhhS[2048 + j];
        float x0 = x[b * 914 + p], x1 = x[b * 914 + 457 + p], pp = (float)p;
        const float* w3r = Wih0 + (size_t)j * 3;
        const float* w3z = Wih0 + (size_t)(1024 + j) * 3;
        const float* w3n = Wih0 + (size_t)(2048 + j) * 3;
        float gir = w3r[0]*x0 + w3r[1]*x1 + w3r[2]*pp + bihS[j];
        float giz = w3z[0]*x0 + w3z[1]*x1 + w3z[2]*pp + bihS[1024 + j];
        float gin = w3n[0]*x0 + w3n[1]*x1 + w3n[2]*pp + bihS[2048 + j];
        float r = 1.f / (1.f + expf(-(gir + ghr)));
        float z = 1.f / (1.f + expf(-(giz + ghz)));
        float n = tanhf(gin + r * ghn);
        float hv = hvS[b * 1024 + j];
        outS[b * 1024 + j] = (1.f - z) * n + z * hv;
      }
    }
  } else if (gateType == 1) {    // dual-source GRU (enc layer1 / dec layer0)
    if (tid < 300) {
      int jl = tid / 50, b = tid - jl * 50;
      int j = j0 + jl;
      if (j < 1024) {
        float gir = acc2[0][jl][b]    + acc2[1][jl][b]    + bihD[j];
        float giz = acc2[0][6+jl][b]  + acc2[1][6+jl][b]  + bihD[1024 + j];
        float gin = acc2[0][12+jl][b] + acc2[1][12+jl][b] + bihD[2048 + j];
        float ghr = acc2[0][18+jl][b] + acc2[1][18+jl][b] + bhhD[j];
        float ghz = acc2[0][24+jl][b] + acc2[1][24+jl][b] + bhhD[1024 + j];
        float ghn = acc2[0][30+jl][b] + acc2[1][30+jl][b] + bhhD[2048 + j];
        float r = 1.f / (1.f + expf(-(gir + ghr)));
        float z = 1.f / (1.f + expf(-(giz + ghz)));
        float n = tanhf(gin + r * ghn);
        float hv = hvD[b * 1024 + j];
        float h2 = (1.f - z) * n + z * hv;
        outD[b * 1024 + j] = h2;
        if (mode == 0) encD[b * 1024 + j] = h2;
      }
    }
  } else if (gateType == 2) {    // gh1 -> scratch, no gate
    // 36 rows x 50 batches = 1800 entries, only 1024 threads -> strided loop
    for (int e2 = tid; e2 < 1800; e2 += 1024) {
      int lr = e2 / 50, b = e2 - lr * 50;
      int g = lr / 12, jl = lr - g * 12;
      int j = j0 + jl;
      if (j < 1024)
        scr_w[(size_t)(g * 1024 + j) * 64 + b] = acc2[0][lr][b] + acc2[1][lr][b];
    }
  } else if (gateType == 3) {    // gi1 + scratch gh -> gate -> h1new + comb
    if (tid < 600) {
      int jl = tid / 50, b = tid - jl * 50;
      int j = j0 + jl;
      if (j < 1024) {
        float gir = acc2[0][jl][b]    + acc2[1][jl][b]    + bihS[j];
        float giz = acc2[0][12+jl][b] + acc2[1][12+jl][b] + bihS[1024 + j];
        float gin = acc2[0][24+jl][b] + acc2[1][24+jl][b] + bihS[2048 + j];
        float ghr = scr_r[(size_t)j * 64 + b]          + bhhS[j];
        float ghz = scr_r[(size_t)(1024 + j) * 64 + b] + bhhS[1024 + j];
        float ghn = scr_r[(size_t)(2048 + j) * 64 + b] + bhhS[2048 + j];
        float r = 1.f / (1.f + expf(-(gir + ghr)));
        float z = 1.f / (1.f + expf(-(giz + ghz)));
        float n = tanhf(gin + r * ghn);
        float hv = hvS[b * 1024 + j];
        float h2 = (1.f - z) * n + z * hv;
        outS[b * 1024 + j] = h2;
        comb[b * 2048 + j] = h2;
      }
    }
  } else {                        // attn relu
    if (tid < 600) {
      int lr = tid / 50, b = tid - lr * 50;
      int o = j0 + lr;
      if (o < 1024) {
        float v = acc2[0][lr][b] + acc2[1][lr][b] + bihS[o];
        outS[b * 1024 + o] = fmaxf(v, 0.f);
      }
    }
  }
}

// ---------------------------------------------------------------------------
__global__ __launch_bounds__(256) void score_kernel(
    const float* __restrict__ enc, const float* __restrict__ comb,
    float* __restrict__ sc)
{
  int gw = (blockIdx.x * 256 + threadIdx.x) >> 6;
  int lane = threadIdx.x & 63;
  if (gw >= BB * SS) return;
  int b = gw / SS, s = gw - b * SS;
  const float* e = enc + ((size_t)s * BB + b) * HD;
  const float* q = comb + (size_t)b * 2048;
  float a = 0.f;
#pragma unroll
  for (int i = 0; i < 16; i++) a += e[lane + 64 * i] * q[lane + 64 * i];
  for (int off = 32; off; off >>= 1) a += __shfl_down(a, off);
  if (!lane) sc[b * SS + s] = a;
}

// softmax over S per batch row fused with attention mix; grid = 50 b x 5 j-slices
__global__ __launch_bounds__(256) void softmax_amix_kernel(
    const float* __restrict__ sc, const float* __restrict__ enc,
    float* __restrict__ comb, float* __restrict__ attn_out, int t)
{
  __shared__ float w[SS];
  __shared__ float red[256];
  int blk = blockIdx.x; int b = blk / 5, sl = blk - b * 5;
  int tid = threadIdx.x;
  float m = -1e30f;
  for (int s = tid; s < SS; s += 256) { float v = sc[b * SS + s]; w[s] = v; m = fmaxf(m, v); }
  red[tid] = m; __syncthreads();
  for (int o = 128; o; o >>= 1) { if (tid < o) red[tid] = fmaxf(red[tid], red[tid + o]); __syncthreads(); }
  m = red[0]; __syncthreads();
  float sum = 0.f;
  for (int s = tid; s < SS; s += 256) { float e = expf(w[s] - m); w[s] = e; sum += e; }
  red[tid] = sum; __syncthreads();
  for (int o = 128; o; o >>= 1) { if (tid < o) red[tid] += red[tid + o]; __syncthreads(); }
  float inv = 1.f / red[0];
  __syncthreads();
  for (int s = tid; s < SS; s += 256) w[s] *= inv;
  __syncthreads();
  if (sl == 0)
    for (int s = tid; s < SS; s += 256) attn_out[((size_t)b * SS + s) * TT + t] = w[s];
  int j0 = sl * 208; int jl = min(208, 1024 - j0);
  if (tid < jl) {
    int j = j0 + tid; float a = 0.f;
#pragma unroll 4
    for (int s = 0; s < SS; s++) a += w[s] * enc[((size_t)s * BB + b) * HD + j];
    comb[(size_t)b * 2048 + HD + j] = a;
  }
}

// logits + argmax, one block per batch row
__global__ __launch_bounds__(256) void logits_argmax_kernel(
    const float* __restrict__ hfc, const float* __restrict__ fcW,
    const float* __restrict__ fcb, float* __restrict__ outv, int t,
    int* __restrict__ tok)
{
  __shared__ float lg[32];
  int b = blockIdx.x, tid = threadIdx.x;
  int wv = tid >> 6, lane = tid & 63;
  const float* hb = hfc + (size_t)b * HD;
  for (int v = wv; v < VV; v += 4) {
    const float* wr = fcW + (size_t)v * HD;
    float a = 0.f;
#pragma unroll
    for (int i = 0; i < 16; i++) a += hb[lane + 64 * i] * wr[lane + 64 * i];
    for (int off = 32; off; off >>= 1) a += __shfl_down(a, off);
    if (!lane) lg[v] = a + fcb[v];
  }
  __syncthreads();
  if (tid == 0) {
    float best = lg[0]; int bi = 0;
    for (int v = 1; v < VV; v++) { if (lg[v] > best) { best = lg[v]; bi = v; } }
    tok[b] = bi;
  }
  if (tid < VV) outv[((size_t)b * TT + t) * VV + tid] = lg[tid];
}

__global__ __launch_bounds__(256) void init_kernel(float* __restrict__ hbufs,
                                                   int* __restrict__ tok)
{
  int i = blockIdx.x * 256 + threadIdx.x;
  if (i < 204800) hbufs[i] = 0.f;
  if (i < BB) tok[i] = 0;
}

__global__ __launch_bounds__(256) void hidcopy_kernel(
    const float* __restrict__ h0, const float* __restrict__ h1,
    float* __restrict__ outh)
{
  int i = blockIdx.x * 256 + threadIdx.x;
  if (i < 51200) { outh[i] = h0[i]; outh[51200 + i] = h1[i]; }
}

// ---------------------------------------------------------------------------
extern "C" void kernel_launch(void* const* d_in, const int* in_sizes, int n_in,
                              void* d_out, int out_size, void* d_ws, size_t ws_size,
                              hipStream_t stream)
{
  const float* x     = (const float*)d_in[0];
  const float* emb   = (const float*)d_in[1];
  const float* eWih0 = (const float*)d_in[2];
  const float* eWhh0 = (const float*)d_in[3];
  const float* ebih0 = (const float*)d_in[4];
  const float* ebhh0 = (const float*)d_in[5];
  const float* eWih1 = (const float*)d_in[6];
  const float* eWhh1 = (const float*)d_in[7];
  const float* ebih1 = (const float*)d_in[8];
  const float* ebhh1 = (const float*)d_in[9];
  const float* dWih  = (const float*)d_in[10];
  const float* dWhh  = (const float*)d_in[11];
  const float* dbih  = (const float*)d_in[12];
  const float* dbhh  = (const float*)d_in[13];
  const float* attnW = (const float*)d_in[14];
  const float* attnB = (const float*)d_in[15];
  const float* fcW   = (const float*)d_in[16];
  const float* fcB   = (const float*)d_in[17];
  float* out = (float*)d_out;

  float* ws = (float*)d_ws;
  float* h0b[2] = { ws,          ws + 51200 };
  float* h1b[2] = { ws + 102400, ws + 153600 };
  float* enc    = ws + 204800;                       // 457*50*1024
  float* scr    = enc + (size_t)SS * BB * HD;        // 3072*64
  float* comb   = scr + 3072 * 64;                   // 50*2048
  float* scoreb = comb + BB * 2048;                  // 50*457
  float* hfc    = scoreb + BB * SS;                  // 50*1024
  int*   tok    = (int*)(hfc + BB * HD);

  float* out_vec  = out;                 // (B,T,V)
  float* out_hid  = out + BB * TT * VV;  // (2,B,H)
  float* out_attn = out_hid + 2 * BB * HD; // (B,S,T)

  const float* dWih1 = dWih + (size_t)3072 * 1024;
  const float* dWhh1 = dWhh + (size_t)3072 * 1024;
  const float* dbih1 = dbih + 3072;
  const float* dbhh1 = dbhh + 3072;

  init_kernel<<<800, 256, 0, stream>>>(ws, tok);

  // ---- encoder: 458 pipelined phases; phase p computes h0[p] and h1[p-1] ----
  for (int p = 0; p <= 457; ++p) {
    float* h0r = h0b[(p + 1) & 1]; float* h0w = h0b[p & 1];
    float* h1r = h1b[p & 1];       float* h1w = h1b[(p + 1) & 1];
    float* encp = enc + (size_t)(p > 0 ? p - 1 : 0) * BB * HD;
    rowdot_kernel<9><<<257, 1024, 0, stream>>>(
        0, p,
        eWhh0, h0r, ebih0, ebhh0, h0r, h0w,
        eWih1, eWhh1, h0r, h1r, ebih1, ebhh1, h1r, h1w, encp,
        x, eWih0, emb, tok, nullptr, nullptr, nullptr);
  }

  // ---- decoder ----
  for (int t = 0; t < TT; ++t) {
    float* h0r = h0b[t & 1]; float* h0w = h0b[(t + 1) & 1];
    float* h1r = h1b[t & 1]; float* h1w = h1b[(t + 1) & 1];

    // D1: dec layer0 (dual, emb gather) + gh1 -> scratch
    rowdot_kernel<9><<<257, 1024, 0, stream>>>(
        1, t,
        dWhh1, h1r, nullptr, nullptr, nullptr, nullptr,
        dWih, dWhh, nullptr, h0r, dbih, dbhh, h0r, h0w, nullptr,
        nullptr, nullptr, emb, tok, nullptr, scr, nullptr);

    // D2: gi1 + gate -> h1new + comb[:,0:1024]
    rowdot_kernel<9><<<86, 1024, 0, stream>>>(
        2, t,
        dWih1, h0w, dbih1, dbhh1, h1r, h1w,
        nullptr, nullptr, nullptr, nullptr, nullptr, nullptr, nullptr, nullptr, nullptr,
        nullptr, nullptr, emb, tok, scr, nullptr, comb);

    score_kernel<<<(BB * SS * 64 + 255) / 256, 256, 0, stream>>>(enc, comb, scoreb);
    softmax_amix_kernel<<<250, 256, 0, stream>>>(scoreb, enc, comb, out_attn, t);

    // attn_fc + relu -> hfc
    rowdot_kernel<3><<<86, 1024, 0, stream>>>(
        3, t,
        attnW, comb, attnB, nullptr, nullptr, hfc,
        nullptr, nullptr, nullptr, nullptr, nullptr, nullptr, nullptr, nullptr, nullptr,
        nullptr, nullptr, emb, tok, nullptr, nullptr, nullptr);

    logits_argmax_kernel<<<BB, 256, 0, stream>>>(hfc, fcW, fcB, out_vec, t, tok);
  }

  hidcopy_kernel<<<200, 256, 0, stream>>>(h0b[0], h1b[0], out_hid);
}

// Round 5
// 32986.578 us; speedup vs baseline: 2.5010x; 2.5010x over previous
//
#include <hip/hip_runtime.h>
#include <math.h>

#define HD 1024
#define BB 50
#define SS 457
#define TT 32
#define VV 27

#define SSTR 68   // Sk row stride (dwords); %4==0 for b128 alignment, %32==4 -> 2-way max on reads
#define WSTR 68

enum { G_ENC0 = 0, G_GRU = 1, G_SCR = 2, G_SCRGATE = 3, G_RELU = 4 };

struct Role {
  const float* srcA; const float* srcB;
  const float* Wa;   const float* Wb;
  const float* bih;  const float* bhh;
  const float* hv;   const float* scr;
  float* out; float* out2; float* scrw;
  int strA, strB, wstrA, K, gate, rowsLinear, gatherA, nsA, nsB;
};

// ---------------------------------------------------------------------------
// Fused tile-GEMM + GRU gate. 256 threads = (tx 0..3 = j, ty 0..15 = 4-batch
// group, kh 0..3 = k-split wave). Thread owns j = j0+tx for ALL 3 gates x 4
// batches. All operands staged global->LDS via vector loads (vmcnt path);
// NO wave-uniform global loads in the inner loop (round-3 lesson).
// n-gate input/hidden halves kept in separate accumulators (aN2 = input half,
// aN3 = hidden half) selected by a block-uniform branch (no runtime reg idx).
// ---------------------------------------------------------------------------
__global__ __launch_bounds__(256) void fused_gemm(
    Role r0, Role r1, int split, int skipRole, int p,
    const float* __restrict__ x, const float* __restrict__ Wih0,
    const float* __restrict__ emb, const int* __restrict__ tok)
{
  __shared__ __align__(16) float Sk[64][SSTR];        // [k-in-window][batch]
  __shared__ __align__(16) float Wt[12][WSTR];        // [gate*4+tx][k-in-window]
  __shared__ __align__(16) float part[4][16][4][4][4];// [kh][ty][tx][slot][bi]

  const int blk = blockIdx.x;
  const int roleId = split ? (blk & 1) : 0;
  if (roleId == skipRole) return;
  const Role& R = roleId ? r1 : r0;
  const int bi2 = split ? (blk >> 1) : blk;
  const int j0 = bi2 * (R.rowsLinear ? 12 : 4);

  const int tid = threadIdx.x;
  const int tx = tid & 3;
  const int ty = (tid >> 2) & 15;
  const int kh = tid >> 6;

  float aR[4] = {0,0,0,0}, aZ[4] = {0,0,0,0}, aN2[4] = {0,0,0,0}, aN3[4] = {0,0,0,0};

  const int nit = R.K >> 6;

  for (int it = 0; it < nit; ++it) {
    const int kw = it << 6;
    const bool second = (R.srcB != nullptr) && (kw >= 1024);
    const int kloc = second ? (kw - 1024) : kw;

    // ---- global loads into registers ----
    float4 sv[4];
#pragma unroll
    for (int u = 0; u < 4; ++u) {
      int e = tid + (u << 8);
      int b = e >> 4, f4 = e & 15;
      int bc = b < BB ? b : BB - 1;
      const float* rp;
      if (second)         rp = R.srcB + (size_t)bc * R.strB + kloc;
      else if (R.gatherA) rp = emb + (size_t)tok[bc] * HD + kw;
      else                rp = R.srcA + (size_t)bc * R.strA + kw;
      sv[u] = *(const float4*)(rp + (f4 << 2));
    }
    float4 wv = make_float4(0.f, 0.f, 0.f, 0.f);
    if (tid < 192) {
      int r = tid >> 4, f4 = tid & 15;
      int wrow;
      if (R.rowsLinear) { int j = j0 + r; wrow = j < 1024 ? j : 1023; }
      else { int g = r >> 2, jj = r & 3; int j = j0 + jj; if (j > 1023) j = 1023;
             wrow = g * 1024 + j; }
      const float* wp = second ? (R.Wb + (size_t)wrow * 1024 + kloc)
                               : (R.Wa + (size_t)wrow * R.wstrA + kw);
      wv = *(const float4*)(wp + (f4 << 2));
    }

    __syncthreads();   // previous window fully consumed
#pragma unroll
    for (int u = 0; u < 4; ++u) {
      int e = tid + (u << 8);
      int b = e >> 4, f4 = e & 15;
      int k = f4 << 2;
      Sk[k + 0][b] = sv[u].x;
      Sk[k + 1][b] = sv[u].y;
      Sk[k + 2][b] = sv[u].z;
      Sk[k + 3][b] = sv[u].w;
    }
    if (tid < 192) {
      int r = tid >> 4, f4 = tid & 15;
      *(float4*)&Wt[r][f4 << 2] = wv;
    }
    __syncthreads();

    const bool ns2 = second ? (R.nsB == 2) : (R.nsA == 2);
#define FMA4(A, wc, s) { A[0] = fmaf(wc, s.x, A[0]); A[1] = fmaf(wc, s.y, A[1]); \
                         A[2] = fmaf(wc, s.z, A[2]); A[3] = fmaf(wc, s.w, A[3]); }
#define CBLOCK(AN) \
    _Pragma("unroll") \
    for (int k4 = 0; k4 < 4; ++k4) { \
      const int kk = (kh << 4) + (k4 << 2); \
      float4 w0 = *(const float4*)&Wt[tx][kk]; \
      float4 w1 = *(const float4*)&Wt[4 + tx][kk]; \
      float4 w2 = *(const float4*)&Wt[8 + tx][kk]; \
      float4 s0 = *(const float4*)&Sk[kk + 0][ty << 2]; \
      float4 s1 = *(const float4*)&Sk[kk + 1][ty << 2]; \
      float4 s2 = *(const float4*)&Sk[kk + 2][ty << 2]; \
      float4 s3 = *(const float4*)&Sk[kk + 3][ty << 2]; \
      FMA4(aR, w0.x, s0) FMA4(aR, w0.y, s1) FMA4(aR, w0.z, s2) FMA4(aR, w0.w, s3) \
      FMA4(aZ, w1.x, s0) FMA4(aZ, w1.y, s1) FMA4(aZ, w1.z, s2) FMA4(aZ, w1.w, s3) \
      FMA4(AN, w2.x, s0) FMA4(AN, w2.y, s1) FMA4(AN, w2.z, s2) FMA4(AN, w2.w, s3) \
    }
    if (ns2) { CBLOCK(aN2) } else { CBLOCK(aN3) }
    __syncthreads();   // before next window overwrites Sk/Wt
  }

  // deterministic k-split reduction via LDS slabs
  *(float4*)&part[kh][ty][tx][0][0] = make_float4(aR[0], aR[1], aR[2], aR[3]);
  *(float4*)&part[kh][ty][tx][1][0] = make_float4(aZ[0], aZ[1], aZ[2], aZ[3]);
  *(float4*)&part[kh][ty][tx][2][0] = make_float4(aN2[0], aN2[1], aN2[2], aN2[3]);
  *(float4*)&part[kh][ty][tx][3][0] = make_float4(aN3[0], aN3[1], aN3[2], aN3[3]);
  __syncthreads();

  if (tid < 200) {
    int b = tid >> 2, jj = tid & 3;
    int py = b >> 2, pi = b & 3;
    float d0 = 0.f, d1 = 0.f, d2 = 0.f, d3 = 0.f;
#pragma unroll
    for (int q = 0; q < 4; ++q) {
      d0 += part[q][py][jj][0][pi];
      d1 += part[q][py][jj][1][pi];
      d2 += part[q][py][jj][2][pi];
      d3 += part[q][py][jj][3][pi];
    }
    if (R.gate == G_ENC0) {
      int j = j0 + jj;
      float x0 = x[b * 914 + p], x1 = x[b * 914 + 457 + p], pf = (float)p;
      const float* w3r = Wih0 + (size_t)j * 3;
      const float* w3z = Wih0 + (size_t)(1024 + j) * 3;
      const float* w3n = Wih0 + (size_t)(2048 + j) * 3;
      float gir = w3r[0]*x0 + w3r[1]*x1 + w3r[2]*pf + R.bih[j];
      float giz = w3z[0]*x0 + w3z[1]*x1 + w3z[2]*pf + R.bih[1024 + j];
      float gin = w3n[0]*x0 + w3n[1]*x1 + w3n[2]*pf + R.bih[2048 + j];
      float rr = 1.f / (1.f + expf(-(gir + d0 + R.bhh[j])));
      float zz = 1.f / (1.f + expf(-(giz + d1 + R.bhh[1024 + j])));
      float nn = tanhf(gin + rr * (d3 + R.bhh[2048 + j]));
      float hv = R.hv[b * 1024 + j];
      R.out[b * 1024 + j] = (1.f - zz) * nn + zz * hv;
    } else if (R.gate == G_GRU) {
      int j = j0 + jj;
      float rr = 1.f / (1.f + expf(-(d0 + R.bih[j] + R.bhh[j])));
      float zz = 1.f / (1.f + expf(-(d1 + R.bih[1024 + j] + R.bhh[1024 + j])));
      float nn = tanhf(d2 + R.bih[2048 + j] + rr * (d3 + R.bhh[2048 + j]));
      float hv = R.hv[b * 1024 + j];
      float h2 = (1.f - zz) * nn + zz * hv;
      R.out[b * 1024 + j] = h2;
      if (R.out2) R.out2[b * 1024 + j] = h2;
    } else if (R.gate == G_SCR) {
      int j = j0 + jj;
      R.scrw[(size_t)j * 64 + b] = d0;
      R.scrw[(size_t)(1024 + j) * 64 + b] = d1;
      R.scrw[(size_t)(2048 + j) * 64 + b] = d3;
    } else if (R.gate == G_SCRGATE) {
      int j = j0 + jj;
      float ghr = R.scr[(size_t)j * 64 + b] + R.bhh[j];
      float ghz = R.scr[(size_t)(1024 + j) * 64 + b] + R.bhh[1024 + j];
      float ghn = R.scr[(size_t)(2048 + j) * 64 + b] + R.bhh[2048 + j];
      float rr = 1.f / (1.f + expf(-(d0 + R.bih[j] + ghr)));
      float zz = 1.f / (1.f + expf(-(d1 + R.bih[1024 + j] + ghz)));
      float nn = tanhf(d2 + R.bih[2048 + j] + rr * ghn);
      float hv = R.hv[b * 1024 + j];
      float h2 = (1.f - zz) * nn + zz * hv;
      R.out[b * 1024 + j] = h2;
      R.out2[b * 2048 + j] = h2;
    } else {  // G_RELU
#pragma unroll
      for (int g = 0; g < 3; ++g) {
        int j = j0 + g * 4 + jj;
        float dg = (g == 0) ? d0 : ((g == 1) ? d1 : d2);
        if (j < 1024) R.out[b * 1024 + j] = fmaxf(dg + R.bih[j], 0.f);
      }
    }
  }
}

// ---------------------------------------------------------------------------
__global__ __launch_bounds__(256) void score_kernel(
    const float* __restrict__ enc, const float* __restrict__ comb,
    float* __restrict__ sc)
{
  int gw = (blockIdx.x * 256 + threadIdx.x) >> 6;
  int lane = threadIdx.x & 63;
  if (gw >= BB * SS) return;
  int b = gw / SS, s = gw - b * SS;
  const float* e = enc + ((size_t)s * BB + b) * HD;
  const float* q = comb + (size_t)b * 2048;
  float a = 0.f;
#pragma unroll
  for (int i = 0; i < 16; i++) a += e[lane + 64 * i] * q[lane + 64 * i];
  for (int off = 32; off; off >>= 1) a += __shfl_down(a, off);
  if (!lane) sc[b * SS + s] = a;
}

__global__ __launch_bounds__(256) void softmax_amix_kernel(
    const float* __restrict__ sc, const float* __restrict__ enc,
    float* __restrict__ comb, float* __restrict__ attn_out, int t)
{
  __shared__ float w[SS];
  __shared__ float red[256];
  int blk = blockIdx.x; int b = blk / 5, sl = blk - b * 5;
  int tid = threadIdx.x;
  float m = -1e30f;
  for (int s = tid; s < SS; s += 256) { float v = sc[b * SS + s]; w[s] = v; m = fmaxf(m, v); }
  red[tid] = m; __syncthreads();
  for (int o = 128; o; o >>= 1) { if (tid < o) red[tid] = fmaxf(red[tid], red[tid + o]); __syncthreads(); }
  m = red[0]; __syncthreads();
  float sum = 0.f;
  for (int s = tid; s < SS; s += 256) { float e = expf(w[s] - m); w[s] = e; sum += e; }
  red[tid] = sum; __syncthreads();
  for (int o = 128; o; o >>= 1) { if (tid < o) red[tid] += red[tid + o]; __syncthreads(); }
  float inv = 1.f / red[0];
  __syncthreads();
  for (int s = tid; s < SS; s += 256) w[s] *= inv;
  __syncthreads();
  if (sl == 0)
    for (int s = tid; s < SS; s += 256) attn_out[((size_t)b * SS + s) * TT + t] = w[s];
  int j0 = sl * 208; int jl = min(208, 1024 - j0);
  if (tid < jl) {
    int j = j0 + tid; float a = 0.f;
#pragma unroll 4
    for (int s = 0; s < SS; s++) a += w[s] * enc[((size_t)s * BB + b) * HD + j];
    comb[(size_t)b * 2048 + HD + j] = a;
  }
}

__global__ __launch_bounds__(256) void logits_argmax_kernel(
    const float* __restrict__ hfc, const float* __restrict__ fcW,
    const float* __restrict__ fcb, float* __restrict__ outv, int t,
    int* __restrict__ tok)
{
  __shared__ float lg[32];
  int b = blockIdx.x, tid = threadIdx.x;
  int wv = tid >> 6, lane = tid & 63;
  const float* hb = hfc + (size_t)b * HD;
  for (int v = wv; v < VV; v += 4) {
    const float* wr = fcW + (size_t)v * HD;
    float a = 0.f;
#pragma unroll
    for (int i = 0; i < 16; i++) a += hb[lane + 64 * i] * wr[lane + 64 * i];
    for (int off = 32; off; off >>= 1) a += __shfl_down(a, off);
    if (!lane) lg[v] = a + fcb[v];
  }
  __syncthreads();
  if (tid == 0) {
    float best = lg[0]; int bi = 0;
    for (int v = 1; v < VV; v++) { if (lg[v] > best) { best = lg[v]; bi = v; } }
    tok[b] = bi;
  }
  if (tid < VV) outv[((size_t)b * TT + t) * VV + tid] = lg[tid];
}

__global__ __launch_bounds__(256) void init_kernel(float* __restrict__ hbufs,
                                                   int* __restrict__ tok)
{
  int i = blockIdx.x * 256 + threadIdx.x;
  if (i < 204800) hbufs[i] = 0.f;
  if (i < BB) tok[i] = 0;
}

__global__ __launch_bounds__(256) void hidcopy_kernel(
    const float* __restrict__ h0, const float* __restrict__ h1,
    float* __restrict__ outh)
{
  int i = blockIdx.x * 256 + threadIdx.x;
  if (i < 51200) { outh[i] = h0[i]; outh[51200 + i] = h1[i]; }
}

// ---------------------------------------------------------------------------
extern "C" void kernel_launch(void* const* d_in, const int* in_sizes, int n_in,
                              void* d_out, int out_size, void* d_ws, size_t ws_size,
                              hipStream_t stream)
{
  const float* x     = (const float*)d_in[0];
  const float* emb   = (const float*)d_in[1];
  const float* eWih0 = (const float*)d_in[2];
  const float* eWhh0 = (const float*)d_in[3];
  const float* ebih0 = (const float*)d_in[4];
  const float* ebhh0 = (const float*)d_in[5];
  const float* eWih1 = (const float*)d_in[6];
  const float* eWhh1 = (const float*)d_in[7];
  const float* ebih1 = (const float*)d_in[8];
  const float* ebhh1 = (const float*)d_in[9];
  const float* dWih  = (const float*)d_in[10];
  const float* dWhh  = (const float*)d_in[11];
  const float* dbih  = (const float*)d_in[12];
  const float* dbhh  = (const float*)d_in[13];
  const float* attnW = (const float*)d_in[14];
  const float* attnB = (const float*)d_in[15];
  const float* fcW   = (const float*)d_in[16];
  const float* fcB   = (const float*)d_in[17];
  float* out = (float*)d_out;

  float* ws = (float*)d_ws;
  float* h0b[2] = { ws,          ws + 51200 };
  float* h1b[2] = { ws + 102400, ws + 153600 };
  float* enc    = ws + 204800;                       // 457*50*1024
  float* scr    = enc + (size_t)SS * BB * HD;        // 3072*64
  float* comb   = scr + 3072 * 64;                   // 50*2048
  float* scoreb = comb + BB * 2048;                  // 50*457
  float* hfc    = scoreb + BB * SS;                  // 50*1024
  int*   tok    = (int*)(hfc + BB * HD);

  float* out_vec  = out;
  float* out_hid  = out + BB * TT * VV;
  float* out_attn = out_hid + 2 * BB * HD;

  const float* dWih1 = dWih + (size_t)3072 * 1024;
  const float* dWhh1 = dWhh + (size_t)3072 * 1024;
  const float* dbih1 = dbih + 3072;
  const float* dbhh1 = dbhh + 3072;

  init_kernel<<<800, 256, 0, stream>>>(ws, tok);

  Role Z{};

  // ---- encoder: phase p computes h0[p] (L0) and h1[p-1] (L1) ----
  for (int p = 0; p <= 457; ++p) {
    float* h0r = h0b[(p + 1) & 1]; float* h0w = h0b[p & 1];
    float* h1r = h1b[p & 1];       float* h1w = h1b[(p + 1) & 1];
    float* encp = enc + (size_t)(p > 0 ? p - 1 : 0) * BB * HD;

    Role L0 = Z;
    L0.srcA = h0r; L0.strA = 1024; L0.Wa = eWhh0; L0.wstrA = 1024;
    L0.bih = ebih0; L0.bhh = ebhh0; L0.hv = h0r; L0.out = h0w;
    L0.K = 1024; L0.gate = G_ENC0; L0.nsA = 3; L0.nsB = 3;

    Role L1 = Z;
    L1.srcA = h0r; L1.strA = 1024; L1.srcB = h1r; L1.strB = 1024;
    L1.Wa = eWih1; L1.wstrA = 1024; L1.Wb = eWhh1;
    L1.bih = ebih1; L1.bhh = ebhh1; L1.hv = h1r;
    L1.out = h1w; L1.out2 = encp;
    L1.K = 2048; L1.gate = G_GRU; L1.nsA = 2; L1.nsB = 3;

    int skip = (p == 0) ? 1 : ((p == 457) ? 0 : -1);
    fused_gemm<<<512, 256, 0, stream>>>(L0, L1, 1, skip, p, x, eWih0, emb, tok);
  }

  // ---- decoder ----
  for (int t = 0; t < TT; ++t) {
    float* h0r = h0b[t & 1]; float* h0w = h0b[(t + 1) & 1];
    float* h1r = h1b[t & 1]; float* h1w = h1b[(t + 1) & 1];

    // D1: dec layer0 (concat emb-gather + h0r) and gh1 -> scr
    Role DL0 = Z;
    DL0.gatherA = 1; DL0.srcB = h0r; DL0.strB = 1024;
    DL0.Wa = dWih; DL0.wstrA = 1024; DL0.Wb = dWhh;
    DL0.bih = dbih; DL0.bhh = dbhh; DL0.hv = h0r; DL0.out = h0w;
    DL0.K = 2048; DL0.gate = G_GRU; DL0.nsA = 2; DL0.nsB = 3;

    Role GH1 = Z;
    GH1.srcA = h1r; GH1.strA = 1024; GH1.Wa = dWhh1; GH1.wstrA = 1024;
    GH1.scrw = scr; GH1.K = 1024; GH1.gate = G_SCR; GH1.nsA = 3; GH1.nsB = 3;

    fused_gemm<<<512, 256, 0, stream>>>(DL0, GH1, 1, -1, t, x, eWih0, emb, tok);

    // D2: gi1 + scr -> gate -> h1w + comb[:,0:1024]
    Role GI1 = Z;
    GI1.srcA = h0w; GI1.strA = 1024; GI1.Wa = dWih1; GI1.wstrA = 1024;
    GI1.bih = dbih1; GI1.bhh = dbhh1; GI1.hv = h1r; GI1.scr = scr;
    GI1.out = h1w; GI1.out2 = comb;
    GI1.K = 1024; GI1.gate = G_SCRGATE; GI1.nsA = 2; GI1.nsB = 2;

    fused_gemm<<<256, 256, 0, stream>>>(GI1, Z, 0, -1, t, x, eWih0, emb, tok);

    score_kernel<<<(BB * SS * 64 + 255) / 256, 256, 0, stream>>>(enc, comb, scoreb);
    softmax_amix_kernel<<<250, 256, 0, stream>>>(scoreb, enc, comb, out_attn, t);

    // attn_fc: hfc = relu(comb @ attnW^T + attnB)
    Role AF = Z;
    AF.srcA = comb; AF.strA = 2048; AF.Wa = attnW; AF.wstrA = 2048;
    AF.bih = attnB; AF.out = hfc;
    AF.K = 2048; AF.gate = G_RELU; AF.rowsLinear = 1; AF.nsA = 2; AF.nsB = 2;

    fused_gemm<<<86, 256, 0, stream>>>(AF, Z, 0, -1, t, x, eWih0, emb, tok);

    logits_argmax_kernel<<<BB, 256, 0, stream>>>(hfc, fcW, fcB, out_vec, t, tok);
  }

  hidcopy_kernel<<<200, 256, 0, stream>>>(h0b[0], h1b[0], out_hid);
}